// Round 8
// baseline (250.351 us; speedup 1.0000x reference)
//
#include <hip/hip_runtime.h>
#include <float.h>

#define NROWS 65536
#define DK 256
#define NCODES 1024
#define FLAG_CAP 8192
#define MARGIN1 0.15f   // f16 single-pass: sigma_d ~0.0065 -> 23 sigma + granule 0.0156
#define D_BIAS 384.0f   // d = enorm + 384 - 2acc in (394, 894): 8-bit pack granule <= 2^-6
#define TIE_EPS 2.0e-3f // fp32 rescan: sigma ~4e-5 -> 50 sigma; ties -> exact fp64 path
#define RB 16           // rows batched per fixup block (amortizes the 1 MB Et sweep)

#define LOSS_OFF 16777216
#define IDX_OFF  16777217

#define CHUNK_STRIDE 1040

// ---------------- ws layout (bytes) ----------------
// High-water 1,356,304 B — identical to R3/R5/R7 (proven in-bounds).
#define WS_FLAG1   0        // int
#define WS_LOSSP   8        // double[64]
#define WS_ENORMD  520      // double[1024] -> ends 8712
#define WS_ENORMF  8720     // float[1024]  -> ends 12816 (16B aligned)
#define WS_FROWS   12816    // int[FLAG_CAP] -> ends 45584
#define WS_IDX     45584    // int[65536]    -> ends 307728
#define WS_EHI     307728   // fp16[1024*256] frag-swizzled (512 KB), dead after dist_fused
#define WS_ET      307728   // float[256][1024] Et (1 MB) OVERLAYS Ehi -> ends 1356304

typedef _Float16 f16x8 __attribute__((ext_vector_type(8)));
typedef float f32x4 __attribute__((ext_vector_type(4)));
typedef unsigned int uint32;

__device__ __forceinline__ uint32 packh2(float a, float b) {
  return (uint32)__builtin_bit_cast(unsigned short, (_Float16)a) |
         ((uint32)__builtin_bit_cast(unsigned short, (_Float16)b) << 16);
}

// ---- init: counters, fp64 E norms, E -> f16 fragment-swizzled Ehi ----
__global__ __launch_bounds__(256) void init_kernel(
    const float* __restrict__ E, double* __restrict__ enorm_d,
    float* __restrict__ enorm_f, uint4* __restrict__ Ehi,
    int* __restrict__ flag1, double* __restrict__ loss_part) {
  const int t = threadIdx.x;
  const int c = blockIdx.x * 8 + (t >> 5);
  const int g = t & 31;  // 8-element group within the code row
  if (blockIdx.x == 0) {
    if (t == 0) *flag1 = 0;
    if (t < 64) loss_part[t] = 0.0;
  }
  const float4* er4 = (const float4*)(E + (size_t)c * DK);
  const float4 va = er4[g * 2];
  const float4 vb = er4[g * 2 + 1];
  double s = (double)va.x * va.x + (double)va.y * va.y + (double)va.z * va.z + (double)va.w * va.w
           + (double)vb.x * vb.x + (double)vb.y * vb.y + (double)vb.z * vb.z + (double)vb.w * vb.w;
  uint4 h;
  h.x = packh2(va.x, va.y);
  h.y = packh2(va.z, va.w);
  h.z = packh2(vb.x, vb.y);
  h.w = packh2(vb.z, vb.w);
  const int ctg = c >> 8, cga = (c >> 4) & 15, col = c & 15;
  const int kc = g >> 2, quad = g & 3;
  Ehi[((size_t)((ctg * 8 + kc) * 16 + cga)) * 64 + (size_t)(quad * 16 + col)] = h;
  #pragma unroll
  for (int m = 1; m < 32; m <<= 1) s += __shfl_xor(s, m, 64);
  if (g == 0) {
    enorm_d[c] = s;
    enorm_f[c] = (float)s;
  }
}

// ---- phase 1 (fused): f16 MFMA distances + top-2 argmin + gather/loss tail ----
__global__ __launch_bounds__(256, 3) void dist_fused(
    const float* __restrict__ X, const uint4* __restrict__ Ehi,
    const float* __restrict__ E, const float* __restrict__ enorm_f,
    int* __restrict__ idx_ws, int* __restrict__ flag1, int* __restrict__ flag_rows,
    float* __restrict__ out, double* __restrict__ loss_part) {
  __shared__ __attribute__((aligned(16))) char lds[33280];
  const int tid = threadIdx.x;
  const int lane = tid & 63;
  const int wid = tid >> 6;
  const int col = lane & 15;
  const int rowBase = blockIdx.x * 64;

  {
    const float4* X4 = (const float4*)X + (size_t)rowBase * 64;
    #pragma unroll
    for (int i = 0; i < 16; ++i) {
      const int f4 = i * 256 + tid;
      const int row = f4 >> 6;
      const int k0 = (f4 & 63) << 2;
      const float4 v = X4[f4];
      uint2 p;
      p.x = packh2(v.x, v.y);
      p.y = packh2(v.z, v.w);
      const int chunk = (row >> 4) * 8 + (k0 >> 5);
      const int off = chunk * CHUNK_STRIDE
                      + (((k0 >> 3) & 3) * 16 + (row & 15)) * 16
                      + ((k0 >> 2) & 1) * 8;
      *(uint2*)(lds + off) = p;
    }
  }
  __syncthreads();

  float rv1[16], rv2[16];
  #pragma unroll
  for (int i = 0; i < 16; ++i) { rv1[i] = FLT_MAX; rv2[i] = FLT_MAX; }

  f32x4 acc[4][4];
  #pragma unroll
  for (int rg = 0; rg < 4; ++rg)
    #pragma unroll
    for (int cg = 0; cg < 4; ++cg) acc[rg][cg] = (f32x4){0.f, 0.f, 0.f, 0.f};

  f16x8 bhA[4], bhB[4];
  auto loadB_ = [&](int t, f16x8* bh) {
    const size_t ub = ((size_t)(t * 16 + wid * 4)) * 64 + (size_t)lane;
    #pragma unroll
    for (int cg = 0; cg < 4; ++cg) bh[cg] = *(const f16x8*)&Ehi[ub + (size_t)cg * 64];
  };
  auto loadA_ = [&](int t, f16x8* av) {
    const int ks = t & 7;
    #pragma unroll
    for (int rg = 0; rg < 4; ++rg)
      av[rg] = *(const f16x8*)(lds + (rg * 8 + ks) * CHUNK_STRIDE + lane * 16);
  };
  auto domfma = [&](f16x8* av, f16x8* bh) {
    #pragma unroll
    for (int rg = 0; rg < 4; ++rg)
      #pragma unroll
      for (int cg = 0; cg < 4; ++cg)
        acc[rg][cg] = __builtin_amdgcn_mfma_f32_16x16x32_f16(av[rg], bh[cg], acc[rg][cg], 0, 0, 0);
  };
  auto epilogue = [&](int ctg) {
    #pragma unroll
    for (int cg = 0; cg < 4; ++cg) {
      const int code = ctg * 256 + wid * 64 + cg * 16 + col;
      const float en = enorm_f[code] + D_BIAS;
      const uint32 li = (uint32)((ctg << 6) | (cg << 4) | col);
      #pragma unroll
      for (int rg = 0; rg < 4; ++rg)
        #pragma unroll
        for (int reg = 0; reg < 4; ++reg) {
          const int i = rg * 4 + reg;
          const float dd = fmaf(-2.0f, acc[rg][cg][reg], en);
          const float p = __builtin_bit_cast(float,
              (__builtin_bit_cast(uint32, dd) & 0xFFFFFF00u) | li);
          rv2[i] = __builtin_amdgcn_fmed3f(p, rv1[i], rv2[i]);
          rv1[i] = fminf(rv1[i], p);
        }
    }
    #pragma unroll
    for (int rg = 0; rg < 4; ++rg)
      #pragma unroll
      for (int cg = 0; cg < 4; ++cg) acc[rg][cg] = (f32x4){0.f, 0.f, 0.f, 0.f};
  };

  loadB_(0, bhA);
  f16x8 av[4];
  for (int tt = 0; tt < 32; tt += 2) {
    loadB_(tt + 1, bhB);
    loadA_(tt, av);
    domfma(av, bhA);
    if (tt + 2 < 32) loadB_(tt + 2, bhA);
    loadA_(tt + 1, av);
    domfma(av, bhB);
    if (((tt + 1) & 7) == 7) epilogue(tt >> 3);
  }

  #pragma unroll
  for (int i = 0; i < 16; ++i) {
    #pragma unroll
    for (int m = 1; m < 16; m <<= 1) {
      const float o1 = __shfl_xor(rv1[i], m, 64);
      const float o2 = __shfl_xor(rv2[i], m, 64);
      rv2[i] = fminf(fminf(rv2[i], o2), fmaxf(rv1[i], o1));
      rv1[i] = fminf(rv1[i], o1);
    }
  }

  __syncthreads();
  float* M = (float*)lds;
  int* idxs = (int*)(lds + 4096);
  if (col == 0) {
    const int quad = lane >> 4;
    #pragma unroll
    for (int i = 0; i < 16; ++i) {
      const int row = (i >> 2) * 16 + quad * 4 + (i & 3);
      M[(row * 4 + wid) * 2 + 0] = rv1[i];
      M[(row * 4 + wid) * 2 + 1] = rv2[i];
    }
  }
  __syncthreads();
  if (tid < 64) {
    const float a1 = M[(tid * 4 + 0) * 2], a2 = M[(tid * 4 + 0) * 2 + 1];
    const float b1 = M[(tid * 4 + 1) * 2], b2 = M[(tid * 4 + 1) * 2 + 1];
    const float c1 = M[(tid * 4 + 2) * 2], c2 = M[(tid * 4 + 2) * 2 + 1];
    const float d1 = M[(tid * 4 + 3) * 2], d2 = M[(tid * 4 + 3) * 2 + 1];
    const float lo1 = fminf(a1, b1), hi1 = fmaxf(a1, b1);
    const float lo2 = fminf(c1, d1), hi2 = fmaxf(c1, d1);
    const float r1 = fminf(lo1, lo2);
    const float s1 = fminf(fmaxf(lo1, lo2), fminf(hi1, hi2));
    const float r2 = fminf(fminf(fminf(a2, b2), fminf(c2, d2)), s1);
    const int w1 = (r1 == a1) ? 0 : (r1 == b1) ? 1 : (r1 == c1) ? 2 : 3;
    const uint32 u1 = __builtin_bit_cast(uint32, r1);
    const int li = (int)(u1 & 255u);
    const int code = ((li >> 6) & 3) * 256 + w1 * 64 + ((li >> 4) & 3) * 16 + (li & 15);
    const int row = rowBase + tid;
    idxs[tid] = code;
    idx_ws[row] = code;
    out[IDX_OFF + row] = (float)code;
    const float q1 = __builtin_bit_cast(float, u1 & 0xFFFFFF00u);
    const float q2 = __builtin_bit_cast(float, __builtin_bit_cast(uint32, r2) & 0xFFFFFF00u);
    if (q2 - q1 < MARGIN1) {
      const int p = atomicAdd(flag1, 1);
      if (p < FLAG_CAP) flag_rows[p] = row;
    }
  }
  __syncthreads();

  const int rsub = tid >> 6, c4 = tid & 63;
  double ls = 0.0;
  #pragma unroll 4
  for (int i = 0; i < 16; ++i) {
    const int rl = i * 4 + rsub;
    const int row = rowBase + rl;
    const int idx = idxs[rl];
    const float4 q = ((const float4*)E)[(size_t)idx * 64 + c4];
    const float4 x = ((const float4*)X)[(size_t)row * 64 + c4];
    ((float4*)out)[(size_t)row * 64 + c4] = q;
    const double d0 = (double)q.x - (double)x.x;
    const double d1 = (double)q.y - (double)x.y;
    const double d2 = (double)q.z - (double)x.z;
    const double d3 = (double)q.w - (double)x.w;
    ls += d0 * d0 + d1 * d1 + d2 * d2 + d3 * d3;
  }
  #pragma unroll
  for (int o = 32; o > 0; o >>= 1) ls += __shfl_down(ls, o, 64);
  __shared__ double wsum[4];
  if ((tid & 63) == 0) wsum[tid >> 6] = ls;
  __syncthreads();
  if (tid == 0)
    atomicAdd(&loss_part[blockIdx.x & 63], wsum[0] + wsum[1] + wsum[2] + wsum[3]);
}

// ---- E transpose (blocks 0..63) + cnt PROBE (block 64) ----
// Probe: dep-FMA chain ~2.8 cyc per flagged row -> this dispatch's dur_us
// directly encodes cnt in the next profile (cnt=8192 ~ 9.5us, 1000 ~ 1.2us).
__global__ __launch_bounds__(256) void transposeE(
    const float* __restrict__ E, float* __restrict__ Et,
    const int* __restrict__ flag1) {
  if (blockIdx.x == 64) {
    if (threadIdx.x == 0) {
      int cnt = *flag1;
      if (cnt > FLAG_CAP) cnt = FLAG_CAP;
      float x = 1.0f;
      for (int i = 0; i < cnt; i += 4) {
        x = fmaf(x, 1.0000001f, 1.0e-7f);
        x = fmaf(x, 0.9999999f, 1.0e-7f);
      }
      asm volatile("" :: "v"(x));  // keep alive (no DCE)
    }
    return;
  }
  __shared__ float tile[64][65];
  const int t = threadIdx.x;
  const int c0 = (blockIdx.x & 15) * 64;
  const int k0 = (blockIdx.x >> 4) * 64;
  {
    const int c = t & 63, q = t >> 6;
    const float4* src = (const float4*)(E + (size_t)(c0 + c) * DK + k0 + q * 16);
    #pragma unroll
    for (int j = 0; j < 4; ++j) {
      const float4 v = src[j];
      const int kk = q * 16 + j * 4;
      tile[kk + 0][c] = v.x;
      tile[kk + 1][c] = v.y;
      tile[kk + 2][c] = v.z;
      tile[kk + 3][c] = v.w;
    }
  }
  __syncthreads();
  {
    const int kk = t >> 2, cq = (t & 3) * 16;
    float4* dst = (float4*)(Et + (size_t)(k0 + kk) * NCODES + c0 + cq);
    #pragma unroll
    for (int j = 0; j < 4; ++j) {
      dst[j] = (float4){tile[kk][cq + j * 4 + 0], tile[kk][cq + j * 4 + 1],
                        tile[kk][cq + j * 4 + 2], tile[kk][cq + j * 4 + 3]};
    }
  }
}

// ---- phase 2: flagged-row re-resolution, RB=16 rows per block ----
// R8 theory: R7's 78us @ 23% VALU / 31% occ / 0 conflicts / ~0 HBM is cache-
// BW + work-volume bound: 1 full 1 MB Et sweep PER ROW. Batch 16 rows per
// sweep: 16 FMA per 4B loaded, Et traffic /16; floor becomes the FLOP count.
// Thread owns 1 code; X rows staged k-major in LDS (stride 36 floats: 16B-
// aligned b128 broadcast reads, conflict-free staged writes).
__global__ __launch_bounds__(1024, 4) void fixup_batch(
    const float* __restrict__ X, const float* __restrict__ E,
    const float* __restrict__ Et, const double* __restrict__ enorm_d,
    const float* __restrict__ enorm_f, const int* __restrict__ flag1,
    const int* __restrict__ flag_rows, const int* __restrict__ idx_ws,
    float* __restrict__ out, double* __restrict__ loss_part) {
  __shared__ __attribute__((aligned(16))) float xsb[256 * 36];  // 36,864 B
  __shared__ float w1s[16][16], w2s[16][16];  // [wave][row]
  __shared__ int wis[16][16];
  __shared__ float g1s[16], g2s[16];
  __shared__ int gis[16];
  __shared__ int rowL[RB], oldL[RB];
  __shared__ double red[256];
  __shared__ double dvs[16];
  __shared__ int dis[16];
  __shared__ int new_sh;

  const int tid = threadIdx.x;  // 0..1023 = code owned
  const int lane = tid & 63, wid = tid >> 6;
  int cnt = *flag1;
  if (cnt > FLAG_CAP) cnt = FLAG_CAP;
  const int ngroups = (cnt + RB - 1) / RB;

  for (int g = blockIdx.x; g < ngroups; g += gridDim.x) {
    const int fbase = g * RB;
    const int nr = min(RB, cnt - fbase);
    __syncthreads();  // protect shared reuse across grid-stride iterations
    if (tid < RB) {
      const int fi = fbase + tid;
      const int row = (tid < nr) ? flag_rows[fi] : flag_rows[fbase];
      rowL[tid] = row;
      oldL[tid] = idx_ws[row];
    }
    __syncthreads();
    // stage 16 X rows k-major: thread = (r = tid&15, kq = tid>>4)
    {
      const int r = tid & 15, kq = tid >> 4;  // kq 0..63
      const float4 v = ((const float4*)X)[(size_t)rowL[r] * 64 + kq];
      const int k0 = kq * 4;
      xsb[(k0 + 0) * 36 + r] = v.x;
      xsb[(k0 + 1) * 36 + r] = v.y;
      xsb[(k0 + 2) * 36 + r] = v.z;
      xsb[(k0 + 3) * 36 + r] = v.w;
    }
    __syncthreads();

    // main scan: per k one coalesced Et load (256 B/wave) + 4 b128 LDS
    // broadcasts + 16 FMA. VALU-bound by design.
    const float* Ecol = Et + tid;
    float acc[16];
    #pragma unroll
    for (int r = 0; r < 16; ++r) acc[r] = 0.f;
    #pragma unroll 2
    for (int k = 0; k < 256; ++k) {
      const float e = Ecol[(size_t)k * NCODES];
      const f32x4* xk4 = (const f32x4*)&xsb[k * 36];
      const f32x4 x0 = xk4[0], x1 = xk4[1], x2 = xk4[2], x3 = xk4[3];
      acc[0] = fmaf(e, x0[0], acc[0]);
      acc[1] = fmaf(e, x0[1], acc[1]);
      acc[2] = fmaf(e, x0[2], acc[2]);
      acc[3] = fmaf(e, x0[3], acc[3]);
      acc[4] = fmaf(e, x1[0], acc[4]);
      acc[5] = fmaf(e, x1[1], acc[5]);
      acc[6] = fmaf(e, x1[2], acc[6]);
      acc[7] = fmaf(e, x1[3], acc[7]);
      acc[8] = fmaf(e, x2[0], acc[8]);
      acc[9] = fmaf(e, x2[1], acc[9]);
      acc[10] = fmaf(e, x2[2], acc[10]);
      acc[11] = fmaf(e, x2[3], acc[11]);
      acc[12] = fmaf(e, x3[0], acc[12]);
      acc[13] = fmaf(e, x3[1], acc[13]);
      acc[14] = fmaf(e, x3[2], acc[14]);
      acc[15] = fmaf(e, x3[3], acc[15]);
    }

    // per-row wave top-2 butterfly (lane0 stores), then 16-wave merge
    const float en = enorm_f[tid];
    #pragma unroll
    for (int r = 0; r < 16; ++r) {
      const float d = fmaf(-2.0f, acc[r], en);
      float v1 = d, v2 = FLT_MAX;
      int i1 = tid;
      #pragma unroll
      for (int m = 1; m < 64; m <<= 1) {
        const float o1 = __shfl_xor(v1, m, 64);
        const float o2 = __shfl_xor(v2, m, 64);
        const int oi = __shfl_xor(i1, m, 64);
        v2 = fminf(fminf(v2, o2), fmaxf(v1, o1));
        if (o1 < v1 || (o1 == v1 && oi < i1)) { v1 = o1; i1 = oi; }
      }
      if (lane == 0) { w1s[wid][r] = v1; w2s[wid][r] = v2; wis[wid][r] = i1; }
    }
    __syncthreads();
    if (tid < 16) {  // thread = row
      float B1 = w1s[0][tid], B2 = w2s[0][tid];
      int I1 = wis[0][tid];
      #pragma unroll
      for (int w = 1; w < 16; ++w) {
        const float o1 = w1s[w][tid], o2 = w2s[w][tid];
        const int oi = wis[w][tid];
        B2 = fminf(fminf(B2, o2), fmaxf(B1, o1));
        if (o1 < B1 || (o1 == B1 && oi < I1)) { B1 = o1; I1 = oi; }
      }
      g1s[tid] = B1;
      g2s[tid] = B2;
      gis[tid] = I1;
    }
    __syncthreads();

    // per-row resolve: rare fp64 tie (coalesced, proven R5/R7 shape) + writeback
    for (int r = 0; r < nr; ++r) {
      int newi = gis[r];
      if (g2s[r] - g1s[r] < TIE_EPS) {  // block-uniform
        double s = 0.0;
        #pragma unroll 8
        for (int k = 0; k < 256; ++k)
          s += (double)Ecol[(size_t)k * NCODES] * (double)xsb[k * 36 + r];
        double bd = enorm_d[tid] - 2.0 * s;
        int bi_ = tid;
        #pragma unroll
        for (int m = 1; m < 64; m <<= 1) {
          const double ov = __shfl_xor(bd, m, 64);
          const int oi = __shfl_xor(bi_, m, 64);
          if (ov < bd || (ov == bd && oi < bi_)) { bd = ov; bi_ = oi; }
        }
        if (lane == 0) { dvs[wid] = bd; dis[wid] = bi_; }
        __syncthreads();
        if (tid == 0) {
          double B = dvs[0];
          int I = dis[0];
          #pragma unroll
          for (int w = 1; w < 16; ++w)
            if (dvs[w] < B || (dvs[w] == B && dis[w] < I)) { B = dvs[w]; I = dis[w]; }
          new_sh = I;
        }
        __syncthreads();
        newi = new_sh;
      }
      const int oldi = oldL[r];
      if (newi != oldi) {  // block-uniform writeback + exact fp64 loss delta
        const int row = rowL[r];
        if (tid < 256) {
          const float x = xsb[tid * 36 + r];
          const float ev = E[(size_t)newi * DK + tid];
          const float eo = E[(size_t)oldi * DK + tid];
          out[(size_t)row * DK + tid] = ev;
          const double dn = (double)ev - (double)x;
          const double dl = (double)eo - (double)x;
          red[tid] = dn * dn - dl * dl;
        }
        __syncthreads();
        for (int off = 128; off > 0; off >>= 1) {
          if (tid < off) red[tid] += red[tid + off];
          __syncthreads();
        }
        if (tid == 0) {
          out[IDX_OFF + row] = (float)newi;
          atomicAdd(&loss_part[row & 63], red[0]);
        }
        __syncthreads();
      }
    }
  }
}

__global__ __launch_bounds__(64) void finalize(
    const double* __restrict__ loss_part, float* __restrict__ out) {
  double v = loss_part[threadIdx.x];
  for (int o = 32; o > 0; o >>= 1) v += __shfl_down(v, o, 64);
  if (threadIdx.x == 0) out[LOSS_OFF] = (float)(v / 16777216.0);
}

extern "C" void kernel_launch(void* const* d_in, const int* in_sizes, int n_in,
                              void* d_out, int out_size, void* d_ws, size_t ws_size,
                              hipStream_t stream) {
  const float* X = (const float*)d_in[0];  // [65536, 256]
  const float* E = (const float*)d_in[1];  // [1024, 256]
  float* out = (float*)d_out;
  char* ws = (char*)d_ws;

  int*    flag1     = (int*)(ws + WS_FLAG1);
  double* loss_part = (double*)(ws + WS_LOSSP);
  double* enorm_d   = (double*)(ws + WS_ENORMD);
  float*  enorm_f   = (float*)(ws + WS_ENORMF);
  int*    flag_rows = (int*)(ws + WS_FROWS);
  int*    idx_ws    = (int*)(ws + WS_IDX);
  uint4*  Ehi       = (uint4*)(ws + WS_EHI);
  float*  Et        = (float*)(ws + WS_ET);

  hipLaunchKernelGGL(init_kernel, dim3(128), dim3(256), 0, stream,
                     E, enorm_d, enorm_f, Ehi, flag1, loss_part);
  hipLaunchKernelGGL(dist_fused, dim3(NROWS / 64), dim3(256), 0, stream,
                     X, Ehi, E, enorm_f, idx_ws, flag1, flag_rows, out, loss_part);
  // Et overlays Ehi (dead after dist_fused); block 64 = cnt probe
  hipLaunchKernelGGL(transposeE, dim3(65), dim3(256), 0, stream, E, Et, flag1);
  hipLaunchKernelGGL(fixup_batch, dim3(FLAG_CAP / RB), dim3(1024), 0, stream,
                     X, E, Et, enorm_d, enorm_f, flag1, flag_rows, idx_ws,
                     out, loss_part);
  hipLaunchKernelGGL(finalize, dim3(1), dim3(64), 0, stream, loss_part, out);
}

// Round 9
// 207.162 us; speedup vs baseline: 1.2085x; 1.2085x over previous
//
#include <hip/hip_runtime.h>
#include <float.h>

#define NROWS 65536
#define DK 256
#define NCODES 1024
#define FLAG_CAP 8192
#define MARGIN1 0.15f   // f16 single-pass: sigma_d ~0.0065 -> 23 sigma + granule 0.0156
#define D_BIAS 384.0f   // d = enorm + 384 - 2acc in (394, 894): 8-bit pack granule <= 2^-6

#define LOSS_OFF 16777216
#define IDX_OFF  16777217

#define CHUNK_STRIDE 1040

// ---------------- ws layout (bytes) ----------------
// High-water 1,356,304 B — identical to R3/R5/R7/R8 (proven in-bounds).
#define WS_FLAG1   0        // int
#define WS_LOSSP   8        // double[64]
#define WS_ENORMD  520      // double[1024] -> ends 8712
#define WS_ENORMF  8720     // float[1024]  -> ends 12816 (16B aligned)
#define WS_FROWS   12816    // int[FLAG_CAP] -> ends 45584
#define WS_IDX     45584    // int[65536]    -> ends 307728
#define WS_EHI     307728   // fp16[1024*256] frag-swizzled (512 KB), dead after dist_fused
#define WS_ET      307728   // float[256][1024] Et (1 MB) OVERLAYS Ehi -> ends 1356304

typedef _Float16 f16x8 __attribute__((ext_vector_type(8)));
typedef float f32x4 __attribute__((ext_vector_type(4)));
typedef unsigned int uint32;

__device__ __forceinline__ uint32 packh2(float a, float b) {
  return (uint32)__builtin_bit_cast(unsigned short, (_Float16)a) |
         ((uint32)__builtin_bit_cast(unsigned short, (_Float16)b) << 16);
}

// ---- init: counters, fp64 E norms, E -> f16 fragment-swizzled Ehi ----
__global__ __launch_bounds__(256) void init_kernel(
    const float* __restrict__ E, double* __restrict__ enorm_d,
    float* __restrict__ enorm_f, uint4* __restrict__ Ehi,
    int* __restrict__ flag1, double* __restrict__ loss_part) {
  const int t = threadIdx.x;
  const int c = blockIdx.x * 8 + (t >> 5);
  const int g = t & 31;  // 8-element group within the code row
  if (blockIdx.x == 0) {
    if (t == 0) *flag1 = 0;
    if (t < 64) loss_part[t] = 0.0;
  }
  const float4* er4 = (const float4*)(E + (size_t)c * DK);
  const float4 va = er4[g * 2];
  const float4 vb = er4[g * 2 + 1];
  double s = (double)va.x * va.x + (double)va.y * va.y + (double)va.z * va.z + (double)va.w * va.w
           + (double)vb.x * vb.x + (double)vb.y * vb.y + (double)vb.z * vb.z + (double)vb.w * vb.w;
  uint4 h;
  h.x = packh2(va.x, va.y);
  h.y = packh2(va.z, va.w);
  h.z = packh2(vb.x, vb.y);
  h.w = packh2(vb.z, vb.w);
  const int ctg = c >> 8, cga = (c >> 4) & 15, col = c & 15;
  const int kc = g >> 2, quad = g & 3;
  Ehi[((size_t)((ctg * 8 + kc) * 16 + cga)) * 64 + (size_t)(quad * 16 + col)] = h;
  #pragma unroll
  for (int m = 1; m < 32; m <<= 1) s += __shfl_xor(s, m, 64);
  if (g == 0) {
    enorm_d[c] = s;
    enorm_f[c] = (float)s;
  }
}

// ---- phase 1 (fused): f16 MFMA distances + top-2 argmin + gather/loss tail ----
__global__ __launch_bounds__(256, 3) void dist_fused(
    const float* __restrict__ X, const uint4* __restrict__ Ehi,
    const float* __restrict__ E, const float* __restrict__ enorm_f,
    int* __restrict__ idx_ws, int* __restrict__ flag1, int* __restrict__ flag_rows,
    float* __restrict__ out, double* __restrict__ loss_part) {
  __shared__ __attribute__((aligned(16))) char lds[33280];
  const int tid = threadIdx.x;
  const int lane = tid & 63;
  const int wid = tid >> 6;
  const int col = lane & 15;
  const int rowBase = blockIdx.x * 64;

  {
    const float4* X4 = (const float4*)X + (size_t)rowBase * 64;
    #pragma unroll
    for (int i = 0; i < 16; ++i) {
      const int f4 = i * 256 + tid;
      const int row = f4 >> 6;
      const int k0 = (f4 & 63) << 2;
      const float4 v = X4[f4];
      uint2 p;
      p.x = packh2(v.x, v.y);
      p.y = packh2(v.z, v.w);
      const int chunk = (row >> 4) * 8 + (k0 >> 5);
      const int off = chunk * CHUNK_STRIDE
                      + (((k0 >> 3) & 3) * 16 + (row & 15)) * 16
                      + ((k0 >> 2) & 1) * 8;
      *(uint2*)(lds + off) = p;
    }
  }
  __syncthreads();

  float rv1[16], rv2[16];
  #pragma unroll
  for (int i = 0; i < 16; ++i) { rv1[i] = FLT_MAX; rv2[i] = FLT_MAX; }

  f32x4 acc[4][4];
  #pragma unroll
  for (int rg = 0; rg < 4; ++rg)
    #pragma unroll
    for (int cg = 0; cg < 4; ++cg) acc[rg][cg] = (f32x4){0.f, 0.f, 0.f, 0.f};

  f16x8 bhA[4], bhB[4];
  auto loadB_ = [&](int t, f16x8* bh) {
    const size_t ub = ((size_t)(t * 16 + wid * 4)) * 64 + (size_t)lane;
    #pragma unroll
    for (int cg = 0; cg < 4; ++cg) bh[cg] = *(const f16x8*)&Ehi[ub + (size_t)cg * 64];
  };
  auto loadA_ = [&](int t, f16x8* av) {
    const int ks = t & 7;
    #pragma unroll
    for (int rg = 0; rg < 4; ++rg)
      av[rg] = *(const f16x8*)(lds + (rg * 8 + ks) * CHUNK_STRIDE + lane * 16);
  };
  auto domfma = [&](f16x8* av, f16x8* bh) {
    #pragma unroll
    for (int rg = 0; rg < 4; ++rg)
      #pragma unroll
      for (int cg = 0; cg < 4; ++cg)
        acc[rg][cg] = __builtin_amdgcn_mfma_f32_16x16x32_f16(av[rg], bh[cg], acc[rg][cg], 0, 0, 0);
  };
  auto epilogue = [&](int ctg) {
    #pragma unroll
    for (int cg = 0; cg < 4; ++cg) {
      const int code = ctg * 256 + wid * 64 + cg * 16 + col;
      const float en = enorm_f[code] + D_BIAS;
      const uint32 li = (uint32)((ctg << 6) | (cg << 4) | col);
      #pragma unroll
      for (int rg = 0; rg < 4; ++rg)
        #pragma unroll
        for (int reg = 0; reg < 4; ++reg) {
          const int i = rg * 4 + reg;
          const float dd = fmaf(-2.0f, acc[rg][cg][reg], en);
          const float p = __builtin_bit_cast(float,
              (__builtin_bit_cast(uint32, dd) & 0xFFFFFF00u) | li);
          rv2[i] = __builtin_amdgcn_fmed3f(p, rv1[i], rv2[i]);
          rv1[i] = fminf(rv1[i], p);
        }
    }
    #pragma unroll
    for (int rg = 0; rg < 4; ++rg)
      #pragma unroll
      for (int cg = 0; cg < 4; ++cg) acc[rg][cg] = (f32x4){0.f, 0.f, 0.f, 0.f};
  };

  loadB_(0, bhA);
  f16x8 av[4];
  for (int tt = 0; tt < 32; tt += 2) {
    loadB_(tt + 1, bhB);
    loadA_(tt, av);
    domfma(av, bhA);
    if (tt + 2 < 32) loadB_(tt + 2, bhA);
    loadA_(tt + 1, av);
    domfma(av, bhB);
    if (((tt + 1) & 7) == 7) epilogue(tt >> 3);
  }

  #pragma unroll
  for (int i = 0; i < 16; ++i) {
    #pragma unroll
    for (int m = 1; m < 16; m <<= 1) {
      const float o1 = __shfl_xor(rv1[i], m, 64);
      const float o2 = __shfl_xor(rv2[i], m, 64);
      rv2[i] = fminf(fminf(rv2[i], o2), fmaxf(rv1[i], o1));
      rv1[i] = fminf(rv1[i], o1);
    }
  }

  __syncthreads();
  float* M = (float*)lds;
  int* idxs = (int*)(lds + 4096);
  if (col == 0) {
    const int quad = lane >> 4;
    #pragma unroll
    for (int i = 0; i < 16; ++i) {
      const int row = (i >> 2) * 16 + quad * 4 + (i & 3);
      M[(row * 4 + wid) * 2 + 0] = rv1[i];
      M[(row * 4 + wid) * 2 + 1] = rv2[i];
    }
  }
  __syncthreads();
  if (tid < 64) {
    const float a1 = M[(tid * 4 + 0) * 2], a2 = M[(tid * 4 + 0) * 2 + 1];
    const float b1 = M[(tid * 4 + 1) * 2], b2 = M[(tid * 4 + 1) * 2 + 1];
    const float c1 = M[(tid * 4 + 2) * 2], c2 = M[(tid * 4 + 2) * 2 + 1];
    const float d1 = M[(tid * 4 + 3) * 2], d2 = M[(tid * 4 + 3) * 2 + 1];
    const float lo1 = fminf(a1, b1), hi1 = fmaxf(a1, b1);
    const float lo2 = fminf(c1, d1), hi2 = fmaxf(c1, d1);
    const float r1 = fminf(lo1, lo2);
    const float s1 = fminf(fmaxf(lo1, lo2), fminf(hi1, hi2));
    const float r2 = fminf(fminf(fminf(a2, b2), fminf(c2, d2)), s1);
    const int w1 = (r1 == a1) ? 0 : (r1 == b1) ? 1 : (r1 == c1) ? 2 : 3;
    const uint32 u1 = __builtin_bit_cast(uint32, r1);
    const int li = (int)(u1 & 255u);
    const int code = ((li >> 6) & 3) * 256 + w1 * 64 + ((li >> 4) & 3) * 16 + (li & 15);
    const int row = rowBase + tid;
    idxs[tid] = code;
    idx_ws[row] = code;
    out[IDX_OFF + row] = (float)code;
    const float q1 = __builtin_bit_cast(float, u1 & 0xFFFFFF00u);
    const float q2 = __builtin_bit_cast(float, __builtin_bit_cast(uint32, r2) & 0xFFFFFF00u);
    if (q2 - q1 < MARGIN1) {
      const int p = atomicAdd(flag1, 1);
      if (p < FLAG_CAP) flag_rows[p] = row;
    }
  }
  __syncthreads();

  const int rsub = tid >> 6, c4 = tid & 63;
  double ls = 0.0;
  #pragma unroll 4
  for (int i = 0; i < 16; ++i) {
    const int rl = i * 4 + rsub;
    const int row = rowBase + rl;
    const int idx = idxs[rl];
    const float4 q = ((const float4*)E)[(size_t)idx * 64 + c4];
    const float4 x = ((const float4*)X)[(size_t)row * 64 + c4];
    ((float4*)out)[(size_t)row * 64 + c4] = q;
    const double d0 = (double)q.x - (double)x.x;
    const double d1 = (double)q.y - (double)x.y;
    const double d2 = (double)q.z - (double)x.z;
    const double d3 = (double)q.w - (double)x.w;
    ls += d0 * d0 + d1 * d1 + d2 * d2 + d3 * d3;
  }
  #pragma unroll
  for (int o = 32; o > 0; o >>= 1) ls += __shfl_down(ls, o, 64);
  __shared__ double wsum[4];
  if ((tid & 63) == 0) wsum[tid >> 6] = ls;
  __syncthreads();
  if (tid == 0)
    atomicAdd(&loss_part[blockIdx.x & 63], wsum[0] + wsum[1] + wsum[2] + wsum[3]);
}

// ---- E transpose: LDS-tiled 64x64, 64 blocks ----
__global__ __launch_bounds__(256) void transposeE(
    const float* __restrict__ E, float* __restrict__ Et) {
  __shared__ float tile[64][65];
  const int t = threadIdx.x;
  const int c0 = (blockIdx.x & 15) * 64;
  const int k0 = (blockIdx.x >> 4) * 64;
  {
    const int c = t & 63, q = t >> 6;
    const float4* src = (const float4*)(E + (size_t)(c0 + c) * DK + k0 + q * 16);
    #pragma unroll
    for (int j = 0; j < 4; ++j) {
      const float4 v = src[j];
      const int kk = q * 16 + j * 4;
      tile[kk + 0][c] = v.x;
      tile[kk + 1][c] = v.y;
      tile[kk + 2][c] = v.z;
      tile[kk + 3][c] = v.w;
    }
  }
  __syncthreads();
  {
    const int kk = t >> 2, cq = (t & 3) * 16;
    float4* dst = (float4*)(Et + (size_t)(k0 + kk) * NCODES + c0 + cq);
    #pragma unroll
    for (int j = 0; j < 4; ++j) {
      dst[j] = (float4){tile[kk][cq + j * 4 + 0], tile[kk][cq + j * 4 + 1],
                        tile[kk][cq + j * 4 + 2], tile[kk][cq + j * 4 + 3]};
    }
  }
}

// ---- phase 2: fp64 split-k re-resolution, 2 rows per 256-thr block ----
// R8 diagnosis: every fixup since R1 kept k SERIAL per thread -> 256-load
// chain x ~800cyc latency = the 78-102us invariant floor (warm-cache replays
// identical). Here wave w owns k in [64w,64w+64); lane covers 16 codes via 4
// contiguous float4 loads per k (4-deep MLP inherent, chain length 64).
// fp64 accumulation from the start = the old tie path FOR ALL flagged rows
// (identical results: non-tie rows agree trivially, tie rows get exactly the
// old fp64 answer; lowest-idx on exact equality). No tie path remains — it
// was itself a 256-chain floor (~7 rows trigger it at TIE_EPS=2e-3).
// Cross-wave sum via stride-3 (24B) padded LDS: 4-way banks.
__global__ __launch_bounds__(256, 2) void fixup_split(
    const float* __restrict__ X, const float* __restrict__ E,
    const float* __restrict__ Et, const double* __restrict__ enorm_d,
    const int* __restrict__ flag1, const int* __restrict__ flag_rows,
    const int* __restrict__ idx_ws, float* __restrict__ out,
    double* __restrict__ loss_part) {
  __shared__ double pacc[NCODES * 3];  // [code]{r0,r1,pad} 24 KB
  __shared__ double xd[256][2];        // 4 KB
  __shared__ double red[256];          // 2 KB
  __shared__ double wv[4][2];
  __shared__ int wi[4][2];
  __shared__ int rowL[2], oldL[2], newsh[2];
  const int tid = threadIdx.x;
  const int lane = tid & 63, wid = tid >> 6;
  int cnt = *flag1;
  if (cnt > FLAG_CAP) cnt = FLAG_CAP;
  const int ngroups = (cnt + 1) >> 1;

  for (int g = blockIdx.x; g < ngroups; g += gridDim.x) {
    const int fbase = g * 2;
    const int nr = min(2, cnt - fbase);
    __syncthreads();  // protect shared reuse across grid-stride iterations
    if (tid < 2) {
      const int fi = fbase + tid;
      const int row = (tid < nr) ? flag_rows[fi] : flag_rows[fbase];
      rowL[tid] = row;
      oldL[tid] = idx_ws[row];
    }
    __syncthreads();
    xd[tid][0] = (double)X[(size_t)rowL[0] * DK + tid];
    xd[tid][1] = (double)X[(size_t)rowL[1] * DK + tid];
    __syncthreads();

    // split-k fp64 partial dots
    double acc[4][4][2];  // [q][j][r] = 32 doubles
    #pragma unroll
    for (int q = 0; q < 4; ++q)
      #pragma unroll
      for (int j = 0; j < 4; ++j) { acc[q][j][0] = 0.0; acc[q][j][1] = 0.0; }
    const f32x4* Et4 = (const f32x4*)Et;
    #pragma unroll 2
    for (int kk = 0; kk < 64; ++kk) {
      const int k = (wid << 6) + kk;
      f32x4 e[4];
      #pragma unroll
      for (int q = 0; q < 4; ++q)
        e[q] = Et4[(size_t)k * 256 + (lane << 2) + q];
      const double x0 = xd[k][0], x1 = xd[k][1];
      #pragma unroll
      for (int q = 0; q < 4; ++q)
        #pragma unroll
        for (int j = 0; j < 4; ++j) {
          const double ed = (double)e[q][j];
          acc[q][j][0] = fma(ed, x0, acc[q][j][0]);
          acc[q][j][1] = fma(ed, x1, acc[q][j][1]);
        }
    }
    // cross-wave accumulation (sequential, 4 barriers)
    for (int w = 0; w < 4; ++w) {
      if (wid == w) {
        #pragma unroll
        for (int q = 0; q < 4; ++q)
          #pragma unroll
          for (int j = 0; j < 4; ++j) {
            const int c = (lane << 4) + (q << 2) + j;
            if (w == 0) {
              pacc[c * 3 + 0] = acc[q][j][0];
              pacc[c * 3 + 1] = acc[q][j][1];
            } else {
              pacc[c * 3 + 0] += acc[q][j][0];
              pacc[c * 3 + 1] += acc[q][j][1];
            }
          }
      }
      __syncthreads();
    }

    // fp64 distances + block argmin per row (lowest idx wins exact ties)
    double bd[2] = {1e300, 1e300};
    int bi[2] = {0x7fffffff, 0x7fffffff};
    #pragma unroll
    for (int m = 0; m < 4; ++m) {
      const int c = tid + (m << 8);
      const double en = enorm_d[c];
      #pragma unroll
      for (int r = 0; r < 2; ++r) {
        const double d = en - 2.0 * pacc[c * 3 + r];
        if (d < bd[r] || (d == bd[r] && c < bi[r])) { bd[r] = d; bi[r] = c; }
      }
    }
    #pragma unroll
    for (int r = 0; r < 2; ++r) {
      double v = bd[r];
      int i = bi[r];
      #pragma unroll
      for (int m = 1; m < 64; m <<= 1) {
        const double ov = __shfl_xor(v, m, 64);
        const int oi = __shfl_xor(i, m, 64);
        if (ov < v || (ov == v && oi < i)) { v = ov; i = oi; }
      }
      if (lane == 0) { wv[wid][r] = v; wi[wid][r] = i; }
    }
    __syncthreads();
    if (tid < 2) {  // tid = row
      double B = wv[0][tid];
      int I = wi[0][tid];
      #pragma unroll
      for (int w = 1; w < 4; ++w) {
        if (wv[w][tid] < B || (wv[w][tid] == B && wi[w][tid] < I)) {
          B = wv[w][tid];
          I = wi[w][tid];
        }
      }
      newsh[tid] = I;
    }
    __syncthreads();

    // writeback changed rows + exact fp64 loss delta
    for (int r = 0; r < nr; ++r) {
      const int newi = newsh[r];
      const int oldi = oldL[r];
      if (newi != oldi) {  // block-uniform
        const int row = rowL[r];
        const double x = xd[tid][r];  // exact (double of the f32 input)
        const float ev = E[(size_t)newi * DK + tid];
        const float eo = E[(size_t)oldi * DK + tid];
        out[(size_t)row * DK + tid] = ev;
        const double dn = (double)ev - x;
        const double dl = (double)eo - x;
        red[tid] = dn * dn - dl * dl;
        __syncthreads();
        for (int off = 128; off > 0; off >>= 1) {
          if (tid < off) red[tid] += red[tid + off];
          __syncthreads();
        }
        if (tid == 0) {
          out[IDX_OFF + row] = (float)newi;
          atomicAdd(&loss_part[row & 63], red[0]);
        }
        __syncthreads();
      }
    }
  }
}

__global__ __launch_bounds__(64) void finalize(
    const double* __restrict__ loss_part, float* __restrict__ out) {
  double v = loss_part[threadIdx.x];
  for (int o = 32; o > 0; o >>= 1) v += __shfl_down(v, o, 64);
  if (threadIdx.x == 0) out[LOSS_OFF] = (float)(v / 16777216.0);
}

extern "C" void kernel_launch(void* const* d_in, const int* in_sizes, int n_in,
                              void* d_out, int out_size, void* d_ws, size_t ws_size,
                              hipStream_t stream) {
  const float* X = (const float*)d_in[0];  // [65536, 256]
  const float* E = (const float*)d_in[1];  // [1024, 256]
  float* out = (float*)d_out;
  char* ws = (char*)d_ws;

  int*    flag1     = (int*)(ws + WS_FLAG1);
  double* loss_part = (double*)(ws + WS_LOSSP);
  double* enorm_d   = (double*)(ws + WS_ENORMD);
  float*  enorm_f   = (float*)(ws + WS_ENORMF);
  int*    flag_rows = (int*)(ws + WS_FROWS);
  int*    idx_ws    = (int*)(ws + WS_IDX);
  uint4*  Ehi       = (uint4*)(ws + WS_EHI);
  float*  Et        = (float*)(ws + WS_ET);

  hipLaunchKernelGGL(init_kernel, dim3(128), dim3(256), 0, stream,
                     E, enorm_d, enorm_f, Ehi, flag1, loss_part);
  hipLaunchKernelGGL(dist_fused, dim3(NROWS / 64), dim3(256), 0, stream,
                     X, Ehi, E, enorm_f, idx_ws, flag1, flag_rows, out, loss_part);
  // Et overlays Ehi (dead after dist_fused)
  hipLaunchKernelGGL(transposeE, dim3(64), dim3(256), 0, stream, E, Et);
  hipLaunchKernelGGL(fixup_split, dim3(FLAG_CAP / 2), dim3(256), 0, stream,
                     X, E, Et, enorm_d, flag1, flag_rows, idx_ws, out, loss_part);
  hipLaunchKernelGGL(finalize, dim3(1), dim3(64), 0, stream, loss_part, out);
}